// Round 11
// baseline (15.555 us; speedup 1.0000x reference)
//
#include <hip/hip_runtime.h>

typedef __attribute__((ext_vector_type(8))) short bf16x8;
typedef __attribute__((ext_vector_type(4))) float f32x4;

// Problem constants
constexpr int kB   = 4;
constexpr int kC   = 64;
constexpr int kH   = 32;
constexpr int kW   = 32;
constexpr int kO   = 128;
constexpr int kG   = 4;
constexpr int kHW  = kH * kW;   // 1024
constexpr int kSEG = kC * 9;    // 576

constexpr int kWSf = 584;       // wacc fp32 row stride (floats); 584 dwords%32=8
constexpr int kWSb = 1160;      // converted-W bf16 row stride (shorts); 580 dw%32=4 -> 2-way
constexpr int kNW  = 16 * kWSf; // 9344 floats = 2336 float4

// bf16 round-to-nearest-even (no NaN inputs here)
__device__ __forceinline__ unsigned short f2bf(float f) {
    union { float f; unsigned u; } v; v.f = f;
    const unsigned r = v.u + 0x7FFFu + ((v.u >> 16) & 1u);
    return (unsigned short)(r >> 16);
}

// Single fused kernel: per-block cooperative weight build + implicit-GEMM MFMA.
// Grid = 256 blocks x 512 threads (1 block/CU).
// bi: ot = bi&7 (o-tile, XCD class), pxb = bi>>3: b = pxb>>3, rq = pxb&7
// (pixel rows 4rq..4rq+3).
// Weight algebra: dest = repeat(arange(O*G), CS) -> entries for output o are
// e in [o*256,(o+1)*256), g = (e%256)>>6; patch index s = ch*9 + tap;
// W[o][k'] with k' = tap*64 + ch.
// 8 waves = 4 pixel rows x 2 col-halves; wave = 16 px x 16 o, K=576 as
// 18 slices of 32 (slice s: tap = s>>1, ch-half = s&1).
__global__ __launch_bounds__(512) void conv_fused_kernel(
    const float* __restrict__ x,
    const float* __restrict__ means,
    const float* __restrict__ bias,
    const int*   __restrict__ col_idx,
    float* __restrict__ out)
{
    // Overlay: wacc (fp32 16x584 = 37376 B) -> converted bf16 W (rows at
    // kWSb shorts) -> later reused as xs (bf16 6x34x72 = 29376 B).
    __shared__ __align__(16) unsigned char smem[16 * kWSf * 4 + 256];
    float*          wacc = reinterpret_cast<float*>(smem);
    unsigned short* wbf  = reinterpret_cast<unsigned short*>(smem);
    unsigned short* xs   = reinterpret_cast<unsigned short*>(smem);
    float*          mloc = reinterpret_cast<float*>(smem + 16 * kWSf * 4);

    const int bi  = blockIdx.x;
    const int ot  = bi & 7;           // o-tile (XCD class)
    const int pxb = bi >> 3;
    const int b   = pxb >> 3;
    const int rq  = pxb & 7;          // pixel rows 4rq..4rq+3
    const int t   = threadIdx.x;
    const int w   = t >> 6;           // wave 0..7
    const int ln  = t & 63;
    const int ln15 = ln & 15;
    const int g    = ln >> 4;         // k-group 0..3
    const int prl  = w >> 1;          // pixel row local 0..3
    const int c0   = (w & 1) * 16;    // pixel col base

    // ---- A) issue all global loads early ----
    const int4* ci4 = reinterpret_cast<const int4*>(col_idx + ot * 16 * 256);
    int4 civ[2];
    civ[0] = ci4[t];
    civ[1] = ci4[512 + t];
    const float mv = (t < 64) ? means[ot * 64 + t] : 0.f;

    // x slab: rows 4rq-1 .. 4rq+4, 64 ch (t < 384: row6, ch-pair, col-half)
    const int row6  = t >> 6;               // (only meaningful for t<384)
    const int cp    = (t & 63) >> 1;
    const int chalf = t & 1;
    const int ch0   = cp * 2;
    const int hr    = rq * 4 - 1 + row6;
    const bool rowok = (t < 384) && (hr >= 0) && (hr < kH);
    const float* x0 = x + (((size_t)b * kC + ch0) * kH + (rowok ? hr : 0)) * kW;
    const float* x1 = x0 + kHW;
    const int hcb = chalf * 16;

    float4 f0[4], f1[4];
    #pragma unroll
    for (int q = 0; q < 4; ++q) {
        f0[q] = rowok ? *reinterpret_cast<const float4*>(x0 + hcb + q * 4)
                      : make_float4(0.f, 0.f, 0.f, 0.f);
        f1[q] = rowok ? *reinterpret_cast<const float4*>(x1 + hcb + q * 4)
                      : make_float4(0.f, 0.f, 0.f, 0.f);
    }

    // ---- B) zero wacc (float4), publish means ----
    {
        float4* wz = reinterpret_cast<float4*>(wacc);
        #pragma unroll
        for (int q = 0; q < 5; ++q) {
            const int i = q * 512 + t;
            if (i < kNW / 4) wz[i] = make_float4(0.f, 0.f, 0.f, 0.f);
        }
        if (t < 64) mloc[t] = mv;
    }
    __syncthreads();

    // ---- C) weight accumulate: 8 entries/thread via LDS atomics ----
    #pragma unroll
    for (int q = 0; q < 2; ++q) {
        const int* sv = reinterpret_cast<const int*>(&civ[q]);
        #pragma unroll
        for (int j = 0; j < 4; ++j) {
            const int e   = (q * 512 + t) * 4 + j;   // local entry 0..4095
            const int s   = sv[j];
            const int ch  = s / 9;
            const int tap = s - ch * 9;
            atomicAdd(&wacc[(e >> 8) * kWSf + tap * 64 + ch],
                      mloc[(e >> 6) & 63]);
        }
    }
    __syncthreads();

    // ---- D) cooperative in-place fp32 -> bf16 convert (read-all / bar / write-all) ----
    {
        const int crow = t >> 5;          // 0..15
        const int ck0  = (t & 31) * 18;   // 0..558
        float cv[18];
        #pragma unroll
        for (int j = 0; j < 18; ++j) cv[j] = wacc[crow * kWSf + ck0 + j];
        __syncthreads();
        #pragma unroll
        for (int j = 0; j < 9; ++j) {
            const unsigned pk = (unsigned)f2bf(cv[2 * j]) |
                                ((unsigned)f2bf(cv[2 * j + 1]) << 16);
            *reinterpret_cast<unsigned*>(&wbf[crow * kWSb + ck0 + 2 * j]) = pk;
        }
    }
    __syncthreads();

    // ---- E) B fragments into registers ----
    bf16x8 bfr[18];
    #pragma unroll
    for (int s = 0; s < 18; ++s)
        bfr[s] = *reinterpret_cast<const bf16x8*>(
            &wbf[ln15 * kWSb + s * 32 + g * 8]);
    __syncthreads();   // all W reads complete before xs overwrites the region

    // ---- F) write x slab into xs (bf16, ch-line stride 72) ----
    if (t < 384) {
        if (chalf == 0) {
            // c34 = j: j==0 -> hc=-1 (zero); j=1..16 -> hc=0..15
            #pragma unroll
            for (int j = 0; j < 17; ++j) {
                float v0 = 0.f, v1 = 0.f;
                if (j > 0) {
                    const int h = j - 1;
                    v0 = reinterpret_cast<const float*>(&f0[h >> 2])[h & 3];
                    v1 = reinterpret_cast<const float*>(&f1[h >> 2])[h & 3];
                }
                const unsigned pkv =
                    (unsigned)f2bf(v0) | ((unsigned)f2bf(v1) << 16);
                *reinterpret_cast<unsigned*>(
                    &xs[(row6 * 34 + j) * 72 + ch0]) = pkv;
            }
        } else {
            // c34 = 17+j: j=0..15 -> hc=16..31; j==16 -> hc=32 (zero)
            #pragma unroll
            for (int j = 0; j < 17; ++j) {
                float v0 = 0.f, v1 = 0.f;
                if (j < 16) {
                    v0 = reinterpret_cast<const float*>(&f0[j >> 2])[j & 3];
                    v1 = reinterpret_cast<const float*>(&f1[j >> 2])[j & 3];
                }
                const unsigned pkv =
                    (unsigned)f2bf(v0) | ((unsigned)f2bf(v1) << 16);
                *reinterpret_cast<unsigned*>(
                    &xs[(row6 * 34 + 17 + j) * 72 + ch0]) = pkv;
            }
        }
    }
    __syncthreads();

    // ---- G) 18 MFMAs: A = patches (16 px x K32), B = W (K32 x 16 o) ----
    f32x4 acc = {0.f, 0.f, 0.f, 0.f};
    #pragma unroll
    for (int s = 0; s < 18; ++s) {
        const int tap  = s >> 1;
        const int half = s & 1;
        const int kh   = tap / 3;
        const int kw   = tap % 3;
        const int r6   = prl + kh;
        const int c34  = c0 + ln15 + kw;
        const bf16x8 a = *reinterpret_cast<const bf16x8*>(
            &xs[(r6 * 34 + c34) * 72 + half * 32 + g * 8]);
        acc = __builtin_amdgcn_mfma_f32_16x16x32_bf16(a, bfr[s], acc, 0, 0, 0);
    }

    // ---- H) epilogue: D row m = g*4+reg -> px col c0+g*4+reg, D col = o ----
    const int o     = ot * 16 + ln15;
    const float bo  = bias[o];
    const int pxrow = rq * 4 + prl;
    const float4 res = make_float4(acc[0] + bo, acc[1] + bo,
                                   acc[2] + bo, acc[3] + bo);
    *reinterpret_cast<float4*>(
        &out[((size_t)(b * kO + o)) * kHW + pxrow * kW + c0 + g * 4]) = res;
}

extern "C" void kernel_launch(void* const* d_in, const int* in_sizes, int n_in,
                              void* d_out, int out_size, void* d_ws, size_t ws_size,
                              hipStream_t stream)
{
    const float* x       = (const float*)d_in[0];
    const float* means   = (const float*)d_in[1];
    const float* bias    = (const float*)d_in[2];
    const int*   col_idx = (const int*)d_in[3];
    float*       out     = (float*)d_out;

    conv_fused_kernel<<<256, 512, 0, stream>>>(x, means, bias, col_idx, out);
}

// Round 12
// 14.658 us; speedup vs baseline: 1.0612x; 1.0612x over previous
//
#include <hip/hip_runtime.h>

typedef __attribute__((ext_vector_type(8))) short bf16x8;
typedef __attribute__((ext_vector_type(4))) float f32x4;

// Problem constants
constexpr int kB   = 4;
constexpr int kC   = 64;
constexpr int kH   = 32;
constexpr int kW   = 32;
constexpr int kO   = 128;
constexpr int kG   = 4;
constexpr int kHW  = kH * kW;   // 1024
constexpr int kSEG = kC * 9;    // 576
constexpr int kWL  = 584;       // W LDS row stride (bf16): 1168 B == 4 dwords mod 32 banks

// bf16 round-to-nearest-even (no NaN inputs here)
__device__ __forceinline__ unsigned short f2bf(float f) {
    union { float f; unsigned u; } v; v.f = f;
    const unsigned r = v.u + 0x7FFFu + ((v.u >> 16) & 1u);
    return (unsigned short)(r >> 16);
}

// Kernel 1: build W_bf16[o][k'] with k' = tap*64 + ch (tap = kh*3+kw).
// dest = repeat(arange(O*G), CS) -> entries for o are [o*256, (o+1)*256),
// g = (e%256)>>6; patch index s = ch*9 + tap. One block per o.
__global__ __launch_bounds__(256) void build_w_kernel(
    const float* __restrict__ means,
    const int*   __restrict__ col_idx,
    unsigned short* __restrict__ Wg)
{
    __shared__ float wacc[kSEG];
    const int o = blockIdx.x, t = threadIdx.x;

    for (int i = t; i < kSEG; i += 256) wacc[i] = 0.f;
    __syncthreads();

    const int s = col_idx[o * 256 + t];
    atomicAdd(&wacc[s], means[o * kG + (t >> 6)]);
    __syncthreads();

    for (int i = t; i < kSEG; i += 256) {
        const int tap = i >> 6;     // 0..8
        const int ch  = i & 63;
        Wg[o * kSEG + i] = f2bf(wacc[ch * 9 + tap]);  // orig s = ch*9 + tap
    }
}

// Kernel 2: implicit-GEMM MFMA conv, 512 threads, grid 256.
// bi: ot = bi&7 (XCD class -> each XCD owns one o-tile, W L2-resident),
// pxb = bi>>3: b = pxb>>3, rq = pxb&7 -> pixel rows 4rq..4rq+3.
// Block: stage W o-tile (16 x 576 bf16) into LDS (rows padded to 584) +
// x slab (6 halo rows x 34 cols x 64 ch bf16, ch-line padded to 72).
// 8 waves = 4 pixel rows x 2 col-halves; wave = 16 px x 16 o, K=576 as
// 18 slices of 32 (slice s: tap = s>>1, ch-half = s&1).
__global__ __launch_bounds__(512) void conv_mfma_kernel(
    const float* __restrict__ x,
    const unsigned short* __restrict__ Wg,
    const float* __restrict__ bias,
    float* __restrict__ out)
{
    __shared__ unsigned short xs[6 * 34 * 72];   // 29376 B
    __shared__ unsigned short wl[16 * kWL];      // 18688 B

    const int bi  = blockIdx.x;
    const int ot  = bi & 7;           // o-tile (XCD class)
    const int pxb = bi >> 3;
    const int b   = pxb >> 3;
    const int rq  = pxb & 7;          // pixel rows 4rq..4rq+3
    const int t   = threadIdx.x;
    const int w   = t >> 6;           // wave 0..7
    const int ln  = t & 63;
    const int ln15 = ln & 15;
    const int g    = ln >> 4;         // k-group 0..3
    const int prl  = w >> 1;          // pixel row local 0..3
    const int c0   = (w & 1) * 16;    // pixel col base

    // ---- stage W o-tile: 1152 16B chunks, fully coalesced ----
    {
        const uint4* wg4 = reinterpret_cast<const uint4*>(Wg + ot * 16 * kSEG);
        #pragma unroll
        for (int p = 0; p < 3; ++p) {
            const int c = t + p * 512;        // 16B chunk id, 0..1151
            if (c < 1152) {
                const int row = c / 72;
                const int col = c - row * 72;
                *reinterpret_cast<uint4*>(&wl[row * kWL + col * 8]) = wg4[c];
            }
        }
    }

    // ---- stage x slab: rows 4rq-1 .. 4rq+4, cols -1..32, 64 ch ----
    // t < 384: row6 = t>>6, ch-pair cp = (t&63)>>1, col-half = t&1
    if (t < 384) {
        const int row6  = t >> 6;
        const int cp    = (t & 63) >> 1;
        const int chalf = t & 1;
        const int ch0   = cp * 2;
        const int hr    = rq * 4 - 1 + row6;
        const bool rowok = (hr >= 0) && (hr < kH);
        const float* x0 = x + (((size_t)b * kC + ch0) * kH + (rowok ? hr : 0)) * kW;
        const float* x1 = x0 + kHW;
        const int hcb = chalf * 16;

        float4 f0[4], f1[4];
        #pragma unroll
        for (int q = 0; q < 4; ++q) {
            f0[q] = rowok ? *reinterpret_cast<const float4*>(x0 + hcb + q * 4)
                          : make_float4(0.f, 0.f, 0.f, 0.f);
            f1[q] = rowok ? *reinterpret_cast<const float4*>(x1 + hcb + q * 4)
                          : make_float4(0.f, 0.f, 0.f, 0.f);
        }

        if (chalf == 0) {
            // c34 = j: j==0 -> hc=-1 (zero); j=1..16 -> hc=0..15
            #pragma unroll
            for (int j = 0; j < 17; ++j) {
                float v0 = 0.f, v1 = 0.f;
                if (j > 0) {
                    const int h = j - 1;
                    v0 = reinterpret_cast<const float*>(&f0[h >> 2])[h & 3];
                    v1 = reinterpret_cast<const float*>(&f1[h >> 2])[h & 3];
                }
                const unsigned pkv =
                    (unsigned)f2bf(v0) | ((unsigned)f2bf(v1) << 16);
                *reinterpret_cast<unsigned*>(
                    &xs[(row6 * 34 + j) * 72 + ch0]) = pkv;
            }
        } else {
            // c34 = 17+j: j=0..15 -> hc=16..31; j==16 -> hc=32 (zero)
            #pragma unroll
            for (int j = 0; j < 17; ++j) {
                float v0 = 0.f, v1 = 0.f;
                if (j < 16) {
                    v0 = reinterpret_cast<const float*>(&f0[j >> 2])[j & 3];
                    v1 = reinterpret_cast<const float*>(&f1[j >> 2])[j & 3];
                }
                const unsigned pkv =
                    (unsigned)f2bf(v0) | ((unsigned)f2bf(v1) << 16);
                *reinterpret_cast<unsigned*>(
                    &xs[(row6 * 34 + 17 + j) * 72 + ch0]) = pkv;
            }
        }
    }
    __syncthreads();

    // ---- B fragments from LDS (2-way max bank aliasing on b128) ----
    bf16x8 bfr[18];
    #pragma unroll
    for (int s = 0; s < 18; ++s)
        bfr[s] = *reinterpret_cast<const bf16x8*>(
            &wl[ln15 * kWL + s * 32 + g * 8]);

    // ---- 18 MFMAs: A = patches (16 px x K32), B = W (K32 x 16 o) ----
    f32x4 acc = {0.f, 0.f, 0.f, 0.f};
    #pragma unroll
    for (int s = 0; s < 18; ++s) {
        const int tap  = s >> 1;
        const int half = s & 1;
        const int kh   = tap / 3;
        const int kw   = tap % 3;
        const int r6   = prl + kh;
        const int c34  = c0 + ln15 + kw;
        const bf16x8 a = *reinterpret_cast<const bf16x8*>(
            &xs[(r6 * 34 + c34) * 72 + half * 32 + g * 8]);
        acc = __builtin_amdgcn_mfma_f32_16x16x32_bf16(a, bfr[s], acc, 0, 0, 0);
    }

    // ---- epilogue: D row m = g*4+reg -> px col c0+g*4+reg, D col = o ----
    const int o     = ot * 16 + ln15;
    const float bo  = bias[o];
    const int pxrow = rq * 4 + prl;
    const float4 res = make_float4(acc[0] + bo, acc[1] + bo,
                                   acc[2] + bo, acc[3] + bo);
    *reinterpret_cast<float4*>(
        &out[((size_t)(b * kO + o)) * kHW + pxrow * kW + c0 + g * 4]) = res;
}

// Fallback (ws too small): direct single-pass VALU conv, block = (b,o).
__global__ __launch_bounds__(256) void conv_direct_kernel(
    const float* __restrict__ x,
    const float* __restrict__ means,
    const float* __restrict__ bias,
    const int*   __restrict__ col_idx,
    float*       __restrict__ out)
{
    __shared__ float tile[34 * 34];
    __shared__ float wloc[kC * 9];

    const int o = blockIdx.x & (kO - 1);
    const int b = blockIdx.x >> 7;
    const int t = threadIdx.x;

    for (int i = t; i < kC * 9; i += 256) wloc[i] = 0.f;
    __syncthreads();
    {
        const int s = col_idx[o * 256 + t];
        atomicAdd(&wloc[s], means[o * kG + (t >> 6)]);
    }

    const int c  = t & 31;
    const int r0 = (t >> 5) * 4;
    const float* xb = x + (size_t)b * kC * kHW;
    float acc[4] = {0.f, 0.f, 0.f, 0.f};

    for (int ch = 0; ch < kC; ++ch) {
        __syncthreads();
        for (int i = t; i < 34 * 34; i += 256) {
            const int rr = i / 34, cc = i - rr * 34;
            const int hr = rr - 1, hc = cc - 1;
            float v = 0.f;
            if (hr >= 0 && hr < kH && hc >= 0 && hc < kW)
                v = xb[ch * kHW + hr * kW + hc];
            tile[i] = v;
        }
        __syncthreads();
        float wv[9];
        #pragma unroll
        for (int k = 0; k < 9; ++k) wv[k] = wloc[ch * 9 + k];
        float xv[6][3];
        #pragma unroll
        for (int i = 0; i < 6; ++i)
            #pragma unroll
            for (int j = 0; j < 3; ++j)
                xv[i][j] = tile[(r0 + i) * 34 + c + j];
        #pragma unroll
        for (int i = 0; i < 4; ++i)
            #pragma unroll
            for (int kh = 0; kh < 3; ++kh)
                #pragma unroll
                for (int kw = 0; kw < 3; ++kw)
                    acc[i] += wv[kh * 3 + kw] * xv[i + kh][kw];
    }
    const float bo = bias[o];
    #pragma unroll
    for (int i = 0; i < 4; ++i)
        out[((size_t)b * kO + o) * kHW + (r0 + i) * kW + c] = acc[i] + bo;
}

extern "C" void kernel_launch(void* const* d_in, const int* in_sizes, int n_in,
                              void* d_out, int out_size, void* d_ws, size_t ws_size,
                              hipStream_t stream)
{
    const float* x       = (const float*)d_in[0];
    const float* means   = (const float*)d_in[1];
    const float* bias    = (const float*)d_in[2];
    const int*   col_idx = (const int*)d_in[3];
    float*       out     = (float*)d_out;

    constexpr size_t kWBytes = (size_t)kO * kSEG * sizeof(unsigned short); // 144 KB

    if (ws_size >= kWBytes) {
        unsigned short* Wg = (unsigned short*)d_ws;
        build_w_kernel<<<kO, 256, 0, stream>>>(means, col_idx, Wg);
        conv_mfma_kernel<<<256, 512, 0, stream>>>(x, Wg, bias, out);
    } else {
        conv_direct_kernel<<<kB * kO, 256, 0, stream>>>(
            x, means, bias, col_idx, out);
    }
}